// Round 9
// baseline (209.571 us; speedup 1.0000x reference)
//
#include <hip/hip_runtime.h>
#include <hip/hip_fp16.h>

// Tree NN: reps = emb[tokens] (4096 x 128 x 128); 7x: reps = tanh(concat(pairs) @ W_tree^T + b);
// out = root @ W_cls^T + b_cls.
//
// R22: spill-safe TLP doubling on R21's 8-phase schedule.
// Evidence: R21 (clean) = ~33 phase-slots x 2.85us at 2 blocks/CU, 8 waves/CU; R13 = 42 x
// 2.02us at 12 waves/CU. Phase-merge cut per-pair latency 28.3->23.5us but lost block
// overlap. All utilizations <=26%; floors (MFMA 13.6us, VALU ~12, HBM ~21, L3-feed ~25)
// say ~30us is reachable with enough wave overlap. R15/R18/R20's TLP attempts all died
// to VGPR spill (cap < demand), never testing TLP cleanly.
//
//  1. 512-THREAD BLOCKS, 8 waves = wm(2) x wn(4). Each wave keeps R13/R21's proven
//     Wf[2][8]=64-reg shape (2 n-tiles, cols [32*wn,+32)) but owns HALF the m-tiles ->
//     per-wave work halves; total LDS reads unchanged (576 b128/pair; m-split adds no
//     duplication, unlike R15's n-split). LDS 67.6KB -> 2 blocks/CU x 8 waves =
//     16 waves/CU (4/SIMD), 2x R21.
//  2. lb(512,4) -> cap 128. Permanent ~77 (Wf 64 + bias + toks; wc reloaded per pair
//     inside L6). Gather staging split into TWO 4xfloat4 batches: only 16 staging regs
//     live during the in-phase MFMA (sched_barrier(0) pins batch placement) -> transient
//     peak ~120 < 128. This is the R20 failure mode, engineered out.
//  3. Work assignment: L0 wm-split 2/2 m-tiles; L1/L2b wm-split 1/1; L3b/L4b/L5b wm0
//     only; L6(prev)+classifier on wm1 (balances phA: wm0 2mt vs wm1 2mt+L6).
// Schedule/pair (8 barriers, as R21): phA{L6(prev)+L0 s0} phB{out(prev)+L1 s0+gather s1}
//   phC{L0 s1} phD{L1 s1+gather s0'} phE{L2b} phF{L3b} phG{L4b} phH{L5b}.
// Pre-committed: spill gate VGPR 100-128 & WRITE ~96B & FETCH ~134MB. Clean + 60-75us =
// TLP confirmed; clean + >=85us = phase-latency intrinsic -> cross-pair pipelining next.

typedef _Float16 half8 __attribute__((ext_vector_type(8)));
typedef float floatx4 __attribute__((ext_vector_type(4)));

#define STRIDE 264   // 256 + 8 fp16 pad: A-row ds_read_b128 conflict-free
#define UROW   33    // uint4 per row
#define NPAIR  2048

__device__ __forceinline__ float fast_tanh(float x) {
  // No clamp needed: e=inf -> 1; e=0 -> -1. Inputs never NaN.
  float e = __expf(2.f * x);
  return 1.f - 2.f * __builtin_amdgcn_rcpf(e + 1.f);
}

__device__ __forceinline__ unsigned pkrtz(float a, float b) {
  auto h = __builtin_amdgcn_cvt_pkrtz(a, b);   // __fp16 ext_vector(2)
  return __builtin_bit_cast(unsigned, h);
}

// Gather, 512 threads: thread (row=t&63, seg=t>>6) covers leaf 2*row+(seg>>2),
// feature-quarter q=seg&3. Split into 4-float4 batches (16 staging regs each).
// Writes 2 uint4/batch at row*33 + (seg>>2)*16 + q*4 + b*2: consecutive lanes hit
// consecutive rows (132B stride -> distinct banks per 16-lane phase) -> conflict-free.
__device__ __forceinline__ void load4(const float* __restrict__ emb, int tok, int seg,
                                      int b, float4 (&st)[4]) {
  const float4* src = (const float4*)emb + (size_t)tok * 32 + (seg & 3) * 8 + b * 4;
#pragma unroll
  for (int j = 0; j < 4; ++j) st[j] = src[j];
}
__device__ __forceinline__ void cvt_write4(const float4 (&st)[4], _Float16* buf,
                                           int row, int seg, int b) {
  uint4* dst = (uint4*)buf + row * UROW + (seg >> 2) * 16 + (seg & 3) * 4 + b * 2;
#pragma unroll
  for (int j = 0; j < 2; ++j) {
    float4 x = st[2 * j], y = st[2 * j + 1];
    uint4 w;
    w.x = pkrtz(x.x, x.y); w.y = pkrtz(x.z, x.w);
    w.z = pkrtz(y.x, y.y); w.w = pkrtz(y.z, y.w);
    dst[j] = w;
  }
}

// K=256 MFMA for one 16-row m-tile, 2 n-tiles, K-split into 2 independent 4-chains.
// Chain A initialized with bias. A-frag: A[m=lane&15][k=quad*8+j]; B-frag:
// B[k=quad*8+j][n=lane&15]; D: col=lane&15, row=quad*4+reg (learn_hip m89/m91).
__device__ __forceinline__ void mfma_k256(const _Float16* arow, const half8 (&Wf)[2][8],
                                          const float (&bias)[2], floatx4 (&accO)[2]) {
  floatx4 aA[2], aB[2];
#pragma unroll
  for (int i = 0; i < 2; ++i) {
    aA[i] = (floatx4){bias[i], bias[i], bias[i], bias[i]};
    aB[i] = (floatx4){0.f, 0.f, 0.f, 0.f};
  }
#pragma unroll
  for (int ks = 0; ks < 4; ++ks) {
    half8 x0 = *(const half8*)(arow + ks * 32);
    half8 x1 = *(const half8*)(arow + (ks + 4) * 32);
    aA[0] = __builtin_amdgcn_mfma_f32_16x16x32_f16(x0, Wf[0][ks],     aA[0], 0, 0, 0);
    aB[0] = __builtin_amdgcn_mfma_f32_16x16x32_f16(x1, Wf[0][ks + 4], aB[0], 0, 0, 0);
    aA[1] = __builtin_amdgcn_mfma_f32_16x16x32_f16(x0, Wf[1][ks],     aA[1], 0, 0, 0);
    aB[1] = __builtin_amdgcn_mfma_f32_16x16x32_f16(x1, Wf[1][ks + 4], aB[1], 0, 0, 0);
  }
  accO[0] = aA[0] + aB[0];
  accO[1] = aA[1] + aB[1];
}

// Batched level, m-tiles [mbase, mbase+MT_LOC): input row R maps to sample s=R/IN_S,
// local ln=R%IN_S (concat of nodes 2ln,2ln+1 -> out-node ln of sample s). Store:
// out-row (ln>>1)+s*(IN_S>>1), col-half ln&1. MVALID<0 = all rows valid; rows >= MVALID
// are stale (finite tanh/leaf values from earlier phases) and masked at store.
template<int MT_LOC, int IN_S, int MVALID>
__device__ __forceinline__ void level_b(const _Float16* inb, _Float16* outb,
                                        const half8 (&Wf)[2][8], const float (&bias)[2],
                                        int mbase, int nbase, int l15, int quad)
{
#pragma unroll
  for (int m = 0; m < MT_LOC; ++m) {
    floatx4 acc[2];
    mfma_k256(inb + ((mbase + m) * 16 + l15) * STRIDE + quad * 8, Wf, bias, acc);
    const int mrow = (mbase + m) * 16 + quad * 4;
#pragma unroll
    for (int i = 0; i < 2; ++i) {
      const int col = (nbase + i) * 16 + l15;
#pragma unroll
      for (int r = 0; r < 4; ++r) {
        const int node = mrow + r;
        if (MVALID < 0 || node < MVALID) {
          const int s  = node / IN_S;          // IN_S pow2 -> shifts
          const int ln = node % IN_S;
          float v = fast_tanh(acc[i][r]);
          outb[((ln >> 1) + s * (IN_S >> 1)) * STRIDE + (ln & 1) * 128 + col] = (_Float16)v;
        }
      }
    }
  }
}

__global__ __launch_bounds__(512, 4)   // cap 128 VGPR; demand ~120 peak -> no spill
void tree_kernel(const int* __restrict__ tokens,
                 const float* __restrict__ embedding,
                 const float* __restrict__ W_tree,
                 const float* __restrict__ b_tree,
                 const float* __restrict__ W_cls,
                 const float* __restrict__ b_cls,
                 float* __restrict__ out)
{
  __shared__ __align__(16) _Float16 bufA[64 * STRIDE];   // leaves (33.8 KB)
  __shared__ __align__(16) _Float16 bufB[32 * STRIDE];   // L0-out / tail ping (16.9 KB)
  __shared__ __align__(16) _Float16 bufD[32 * STRIDE];   // L1-outs / tail pong (16.9 KB)
  __shared__ float wavepart[4][2][3];                    // classifier partials (96 B)

  const int tid  = threadIdx.x;
  const int wid  = tid >> 6;               // wave id 0-7
  const int lane = tid & 63;
  const int l15  = lane & 15;
  const int quad = lane >> 4;
  const int wn   = wid & 3;                // n-quarter: cols [32*wn, 32*wn+32)
  const int wm   = wid >> 2;               // m-half; wm0 runs small tail, wm1 runs L6
  const int nbase = wn * 2;
  const int row  = tid & 63;               // gather destination row
  const int seg  = tid >> 6;               // gather segment 0-7
  const int tidx = 2 * row + (seg >> 2);   // this thread's token index within a sample

  // ---- stage this wave's 2 n-tiles of W_tree as B-fragments (64 VGPR) ----
  // B[k][n] = W_tree[e=n][h=k]  (einsum 'bnh,eh->bne' => out = comb @ W^T)
  half8 Wf[2][8];
#pragma unroll
  for (int i = 0; i < 2; ++i) {
    const int e = (nbase + i) * 16 + l15;
#pragma unroll
    for (int ks = 0; ks < 8; ++ks) {
      const int k = ks * 32 + quad * 8;
      const float4* p = (const float4*)(W_tree + e * 256 + k);
      float4 lo = p[0], hi = p[1];
      half8 f;
      f[0] = (_Float16)lo.x; f[1] = (_Float16)lo.y; f[2] = (_Float16)lo.z; f[3] = (_Float16)lo.w;
      f[4] = (_Float16)hi.x; f[5] = (_Float16)hi.y; f[6] = (_Float16)hi.z; f[7] = (_Float16)hi.w;
      Wf[i][ks] = f;
    }
  }
  float bias[2];
#pragma unroll
  for (int i = 0; i < 2; ++i) bias[i] = b_tree[(nbase + i) * 16 + l15];

  // ---- prologue: gather s0 of first pair ----
  int tokB_cur = tokens[(2 * blockIdx.x + 1) * 128 + tidx];
  {
    const int tokA0 = tokens[(2 * blockIdx.x) * 128 + tidx];
    float4 st0[4], st1[4];
    load4(embedding, tokA0, seg, 0, st0);
    load4(embedding, tokA0, seg, 1, st1);
    cvt_write4(st0, bufA, row, seg, 0);
    cvt_write4(st1, bufA, row, seg, 1);
  }
  __syncthreads();

#pragma unroll 1
  for (int p = blockIdx.x; p < NPAIR; p += (int)gridDim.x) {
    int pn = p + gridDim.x;
    if (pn >= NPAIR) pn = p;                   // last iter: harmless self-reload
    const bool first = (p == (int)blockIdx.x);
    const int pprev = p - (int)gridDim.x;
    const int tokA_nxt = tokens[(2 * pn) * 128 + tidx];
    const int tokB_nxt = tokens[(2 * pn + 1) * 128 + tidx];

    // ---- phA: wm1: L6b(prev, D rows 0-1)+classifier, L0 s0 mt{2,3}; wm0: L0 mt{0,1} ----
    if (wm == 1) {
      if (!first) {
        floatx4 acc[2];
        mfma_k256(bufD + l15 * STRIDE + quad * 8, Wf, bias, acc);  // rows 0-1 = roots
        float part[2][3] = {{0.f, 0.f, 0.f}, {0.f, 0.f, 0.f}};
        if (quad == 0) {
          float wcl[2][3];                      // reloaded per pair: not in permanent set
#pragma unroll
          for (int i = 0; i < 2; ++i)
#pragma unroll
            for (int o = 0; o < 3; ++o) wcl[i][o] = W_cls[o * 128 + (nbase + i) * 16 + l15];
#pragma unroll
          for (int i = 0; i < 2; ++i)
#pragma unroll
            for (int rr = 0; rr < 2; ++rr) {    // rr = sample
              float v = fast_tanh(acc[i][rr]);
#pragma unroll
              for (int o = 0; o < 3; ++o) part[rr][o] = fmaf(v, wcl[i][o], part[rr][o]);
            }
        }
#pragma unroll
        for (int rr = 0; rr < 2; ++rr)
#pragma unroll
          for (int o = 0; o < 3; ++o) {
            float v = part[rr][o];              // nonzero only in quad-0 lanes
            v += __shfl_down(v, 8);
            v += __shfl_down(v, 4);
            v += __shfl_down(v, 2);
            v += __shfl_down(v, 1);
            if (lane == 0) wavepart[wn][rr][o] = v;
          }
      }
      level_b<2, 64, -1>(bufA, bufB, Wf, bias, 2, nbase, l15, quad);   // L0 mt 2,3
    } else {
      level_b<2, 64, -1>(bufA, bufB, Wf, bias, 0, nbase, l15, quad);   // L0 mt 0,1
    }
    __syncthreads();

    // ---- phB: out(prev); L1 s0: B[0:32] -> D[0:16]; gather s1 -> A ----
    {
      float4 st0[4];
      load4(embedding, tokB_cur, seg, 0, st0);         // batch1 in flight across L1
      __builtin_amdgcn_sched_barrier(0);               // pin: issue before MFMA region
      if (!first && tid < 6) {
        const int rr = tid / 3, o = tid - 3 * rr;
        float v = wavepart[0][rr][o] + wavepart[1][rr][o]
                + wavepart[2][rr][o] + wavepart[3][rr][o];
        out[(2 * pprev + rr) * 3 + o] = v + b_cls[o];
      }
      level_b<1, 32, -1>(bufB, bufD, Wf, bias, wm, nbase, l15, quad);  // L1 s0
      __builtin_amdgcn_sched_barrier(0);               // pin: batch2 stays post-MFMA
      float4 st1[4];
      load4(embedding, tokB_cur, seg, 1, st1);
      cvt_write4(st0, bufA, row, seg, 0);
      cvt_write4(st1, bufA, row, seg, 1);
    }
    __syncthreads();

    // ---- phC: L0 s1: A -> B ----
    level_b<2, 64, -1>(bufA, bufB, Wf, bias, wm * 2, nbase, l15, quad);
    __syncthreads();

    // ---- phD: L1 s1: B -> D[16:32]; gather s0(next pair) -> A ----
    {
      float4 st0[4];
      load4(embedding, tokA_nxt, seg, 0, st0);
      __builtin_amdgcn_sched_barrier(0);
      level_b<1, 32, -1>(bufB, bufD + 16 * STRIDE, Wf, bias, wm, nbase, l15, quad);
      __builtin_amdgcn_sched_barrier(0);
      float4 st1[4];
      load4(embedding, tokA_nxt, seg, 1, st1);
      cvt_write4(st0, bufA, row, seg, 0);
      cvt_write4(st1, bufA, row, seg, 1);
    }
    __syncthreads();

    // ---- phE: L2b: D[0:32] (s0 0-15, s1 16-31) -> B[0:16] ----
    level_b<1, 16, -1>(bufD, bufB, Wf, bias, wm, nbase, l15, quad);
    __syncthreads();

    // ---- phF: L3b (wm0): B[0:16] -> D[0:8] ----
    if (wm == 0) level_b<1, 8, -1>(bufB, bufD, Wf, bias, 0, nbase, l15, quad);
    __syncthreads();

    // ---- phG: L4b (wm0): D[0:8] -> B[0:4]  (m-tile rows 8-15 stale, masked) ----
    if (wm == 0) level_b<1, 4, 8>(bufD, bufB, Wf, bias, 0, nbase, l15, quad);
    __syncthreads();

    // ---- phH: L5b (wm0): B[0:4] -> D[0:2]  (rows 4-15 stale, masked) ----
    if (wm == 0) level_b<1, 2, 4>(bufB, bufD, Wf, bias, 0, nbase, l15, quad);
    __syncthreads();

    tokB_cur = tokB_nxt;
  }

  // ---- epilogue: L6b + classifier + store for the final pair (wm1, as in-loop) ----
  {
    const int plast = (int)blockIdx.x
        + ((NPAIR - 1 - (int)blockIdx.x) / (int)gridDim.x) * (int)gridDim.x;
    if (wm == 1) {
      floatx4 acc[2];
      mfma_k256(bufD + l15 * STRIDE + quad * 8, Wf, bias, acc);
      float part[2][3] = {{0.f, 0.f, 0.f}, {0.f, 0.f, 0.f}};
      if (quad == 0) {
        float wcl[2][3];
#pragma unroll
        for (int i = 0; i < 2; ++i)
#pragma unroll
          for (int o = 0; o < 3; ++o) wcl[i][o] = W_cls[o * 128 + (nbase + i) * 16 + l15];
#pragma unroll
        for (int i = 0; i < 2; ++i)
#pragma unroll
          for (int rr = 0; rr < 2; ++rr) {
            float v = fast_tanh(acc[i][rr]);
#pragma unroll
            for (int o = 0; o < 3; ++o) part[rr][o] = fmaf(v, wcl[i][o], part[rr][o]);
          }
      }
#pragma unroll
      for (int rr = 0; rr < 2; ++rr)
#pragma unroll
        for (int o = 0; o < 3; ++o) {
          float v = part[rr][o];
          v += __shfl_down(v, 8);
          v += __shfl_down(v, 4);
          v += __shfl_down(v, 2);
          v += __shfl_down(v, 1);
          if (lane == 0) wavepart[wn][rr][o] = v;
        }
    }
    __syncthreads();
    if (tid < 6) {
      const int rr = tid / 3, o = tid - 3 * rr;
      float v = wavepart[0][rr][o] + wavepart[1][rr][o]
              + wavepart[2][rr][o] + wavepart[3][rr][o];
      out[(2 * plast + rr) * 3 + o] = v + b_cls[o];
    }
  }
}

extern "C" void kernel_launch(void* const* d_in, const int* in_sizes, int n_in,
                              void* d_out, int out_size, void* d_ws, size_t ws_size,
                              hipStream_t stream) {
  const int*   tokens    = (const int*)d_in[0];
  const float* embedding = (const float*)d_in[1];
  const float* W_tree    = (const float*)d_in[2];
  const float* b_tree    = (const float*)d_in[3];
  const float* W_cls     = (const float*)d_in[4];
  const float* b_cls     = (const float*)d_in[5];
  float* out = (float*)d_out;

  dim3 grid(512), block(512);   // 2 blocks/CU x 256 CUs (LDS 67.6KB); 4 pairs/block exactly
  tree_kernel<<<grid, block, 0, stream>>>(tokens, embedding, W_tree, b_tree, W_cls, b_cls, out);
}

// Round 10
// 183.056 us; speedup vs baseline: 1.1448x; 1.1448x over previous
//
#include <hip/hip_runtime.h>
#include <hip/hip_fp16.h>

// Tree NN: reps = emb[tokens] (4096 x 128 x 128); 7x: reps = tanh(concat(pairs) @ W_tree^T + b);
// out = root @ W_cls^T + b_cls.
//
// R23: R21's phase-merge at R13's occupancy. Evidence chain:
//  - 512-thread blocks spill, always (R15/R18/R20/R22: 4 strikes). TLP via block size closed.
//  - Clean runs: R13 = 42 slots x 2.02us @ 12 waves/CU; R21 = 33 x 2.85 @ 8 waves/CU.
//    Slot cost drops 2.85->2.02 with 12 waves; heavy phases are LDS-pipe-heavy (~4.6k cy
//    per L0 phase), light phases latency-bound -> want fewer slots AND 12 waves.
//  - R21 needed 67.6KB LDS (2 blocks/CU) only for the 32-row D buffer of L1-outs.
//
// R23 fits a 10-phase/pair schedule in A(64)+B(32)+C(6) = 102 rows = 53.9KB + wavepart
// <= 54.6KB -> 3 blocks/CU, 12 waves/CU, lb(256,3) (proven R13 regime, VGPR ~112 < 170).
// Buffer aliasing (per-phase hazards audited):
//  - L1 out -> A[0:16] (leaves dead after L0 read them; disjoint from L1's B read)
//  - L3 out -> B[16:20] (disjoint from its B[0:16] read; stale rows masked at store)
//  - L4 outs -> C[0:2]/C[2:4]; batched L5b C[0:4]->C[4:6]; L6b C[4:6]->classifier.
//  - L5b/L6b/store deferred into NEXT pair's phA/phB/phC (R21's deferred-L6 pattern).
//  - Gathers split into 32-row halves folded into phC/phD (s1) and phG/phI (next s0),
//    each targeting only dead A regions (hi: A[32:64], lo: A[0:32] after L2 consumed
//    A[0:16]). 8xfloat4 staged loads issue first; cvt+write after the phase's MFMA.
// Schedule/pair: phA{L5b(prev)+L0 s0} phB{L6b(prev)+L1 s0} phC{store(prev)+L2 s0+gat s1hi}
//   phD{L3 s0+gat s1lo} phE{L4 s0} phF{L0 s1} phG{L1 s1+gat n0hi} phH{L2 s1}
//   phI{L3 s1+gat n0lo} phJ{L4 s1}  = 10 barriers (vs R13's 14, R21's 8@2blk).
// Makespan: 3 pairs x 10 + ~2 = 32 slots @ ~2.05us = ~66us predicted.
// Pre-committed gates: VGPR 100-140 / WRITE ~96B / FETCH ~123MB = clean. Clean+65-75us =
// model confirmed; clean+>=85us = slot model wrong -> attack per-phase latency next.

typedef _Float16 half8 __attribute__((ext_vector_type(8)));
typedef float floatx4 __attribute__((ext_vector_type(4)));

#define STRIDE 264   // 256 + 8 fp16 pad: A-row ds_read_b128 conflict-free
#define UROW   33    // uint4 per row
#define NPAIR  2048

__device__ __forceinline__ float fast_tanh(float x) {
  // No clamp needed: e=inf -> 1; e=0 -> -1. Inputs never NaN.
  float e = __expf(2.f * x);
  return 1.f - 2.f * __builtin_amdgcn_rcpf(e + 1.f);
}

__device__ __forceinline__ unsigned pkrtz(float a, float b) {
  auto h = __builtin_amdgcn_cvt_pkrtz(a, b);   // __fp16 ext_vector(2)
  return __builtin_bit_cast(unsigned, h);
}

// Half-gather: 256 threads cover 32 pair-rows. Thread t: r=t&31, lb=(t>>7)&1 (leaf bit),
// q=(t>>5)&3 (feature quarter = 32 floats). Token idx within sample: 2*(rowbase+r)+lb.
// Writes 4 uint4 at row*33 + lb*16 + q*4: consecutive lanes hit consecutive rows
// (33-uint4 stride == 132B -> distinct banks per 16-lane phase) -> conflict-free.
__device__ __forceinline__ void load8(const float* __restrict__ emb, int tok, int q,
                                      float4 (&st)[8]) {
  const float4* src = (const float4*)emb + (size_t)tok * 32 + q * 8;
#pragma unroll
  for (int j = 0; j < 8; ++j) st[j] = src[j];
}
__device__ __forceinline__ void cvt_write8(const float4 (&st)[8], _Float16* buf,
                                           int row, int lb, int q) {
  uint4* dst = (uint4*)buf + row * UROW + lb * 16 + q * 4;
#pragma unroll
  for (int j = 0; j < 4; ++j) {
    float4 x = st[2 * j], y = st[2 * j + 1];
    uint4 w;
    w.x = pkrtz(x.x, x.y); w.y = pkrtz(x.z, x.w);
    w.z = pkrtz(y.x, y.y); w.w = pkrtz(y.z, y.w);
    dst[j] = w;
  }
}

// K=256 MFMA for one 16-row m-tile, 2 n-tiles, K-split into 2 independent 4-chains.
// Chain A initialized with bias. A-frag: A[m=lane&15][k=quad*8+j]; B-frag:
// B[k=quad*8+j][n=lane&15]; D: col=lane&15, row=quad*4+reg (learn_hip m89/m91).
__device__ __forceinline__ void mfma_k256(const _Float16* arow, const half8 (&Wf)[2][8],
                                          const float (&bias)[2], floatx4 (&accO)[2]) {
  floatx4 aA[2], aB[2];
#pragma unroll
  for (int i = 0; i < 2; ++i) {
    aA[i] = (floatx4){bias[i], bias[i], bias[i], bias[i]};
    aB[i] = (floatx4){0.f, 0.f, 0.f, 0.f};
  }
#pragma unroll
  for (int ks = 0; ks < 4; ++ks) {
    half8 x0 = *(const half8*)(arow + ks * 32);
    half8 x1 = *(const half8*)(arow + (ks + 4) * 32);
    aA[0] = __builtin_amdgcn_mfma_f32_16x16x32_f16(x0, Wf[0][ks],     aA[0], 0, 0, 0);
    aB[0] = __builtin_amdgcn_mfma_f32_16x16x32_f16(x1, Wf[0][ks + 4], aB[0], 0, 0, 0);
    aA[1] = __builtin_amdgcn_mfma_f32_16x16x32_f16(x0, Wf[1][ks],     aA[1], 0, 0, 0);
    aB[1] = __builtin_amdgcn_mfma_f32_16x16x32_f16(x1, Wf[1][ks + 4], aB[1], 0, 0, 0);
  }
  accO[0] = aA[0] + aB[0];
  accO[1] = aA[1] + aB[1];
}

// Level: MT m-tiles from rows [0,16*MT) of inb. Input row R (node) -> sample s=R/IN_S,
// local ln=R%IN_S; out-row (ln>>1)+s*(IN_S>>1), col-half ln&1 (pair-contiguous).
// MVALID<0 = all rows valid; rows >= MVALID are stale (finite values) -> masked at store.
template<int MT, int IN_S, int MVALID>
__device__ __forceinline__ void level_b(const _Float16* inb, _Float16* outb,
                                        const half8 (&Wf)[2][8], const float (&bias)[2],
                                        int nbase, int l15, int quad)
{
#pragma unroll
  for (int m = 0; m < MT; ++m) {
    floatx4 acc[2];
    mfma_k256(inb + (m * 16 + l15) * STRIDE + quad * 8, Wf, bias, acc);
    const int mrow = m * 16 + quad * 4;
#pragma unroll
    for (int i = 0; i < 2; ++i) {
      const int col = (nbase + i) * 16 + l15;
#pragma unroll
      for (int r = 0; r < 4; ++r) {
        const int node = mrow + r;
        if (MVALID < 0 || node < MVALID) {
          const int s  = node / IN_S;          // IN_S pow2 -> shifts
          const int ln = node % IN_S;
          float v = fast_tanh(acc[i][r]);
          outb[((ln >> 1) + s * (IN_S >> 1)) * STRIDE + (ln & 1) * 128 + col] = (_Float16)v;
        }
      }
    }
  }
}

__global__ __launch_bounds__(256, 3)   // 3 blocks/CU (LDS 53.9KB); cap 170, demand ~135
void tree_kernel(const int* __restrict__ tokens,
                 const float* __restrict__ embedding,
                 const float* __restrict__ W_tree,
                 const float* __restrict__ b_tree,
                 const float* __restrict__ W_cls,
                 const float* __restrict__ b_cls,
                 float* __restrict__ out)
{
  __shared__ __align__(16) _Float16 bufA[64 * STRIDE];   // leaves; rows 0-15 reused as L1-out (33.8 KB)
  __shared__ __align__(16) _Float16 bufB[32 * STRIDE];   // L0-out; rows 16-19 reused as L3-out (16.9 KB)
  __shared__ __align__(16) _Float16 bufC[6 * STRIDE];    // L4-outs [0:4], L5b-outs [4:6] (3.2 KB)
  __shared__ float wavepart[4][2][3];                    // classifier partials (96 B)

  const int tid  = threadIdx.x;
  const int wid  = tid >> 6;
  const int lane = tid & 63;
  const int l15  = lane & 15;
  const int quad = lane >> 4;
  const int nbase = wid * 2;               // this wave's n-tile base (cols [32*wid, +32))
  const int gr   = tid & 31;               // gather row within 32-row half
  const int glb  = (tid >> 7) & 1;         // gather leaf bit
  const int gq   = (tid >> 5) & 3;         // gather feature quarter
  const int li   = 2 * gr + glb;           // token idx for lo half; hi half = li + 64

  // ---- stage this wave's 2 n-tiles of W_tree as B-fragments (64 VGPR) ----
  // B[k][n] = W_tree[e=n][h=k]  (einsum 'bnh,eh->bne' => out = comb @ W^T)
  half8 Wf[2][8];
#pragma unroll
  for (int i = 0; i < 2; ++i) {
    const int e = (nbase + i) * 16 + l15;
#pragma unroll
    for (int ks = 0; ks < 8; ++ks) {
      const int k = ks * 32 + quad * 8;
      const float4* p = (const float4*)(W_tree + e * 256 + k);
      float4 lo = p[0], hi = p[1];
      half8 f;
      f[0] = (_Float16)lo.x; f[1] = (_Float16)lo.y; f[2] = (_Float16)lo.z; f[3] = (_Float16)lo.w;
      f[4] = (_Float16)hi.x; f[5] = (_Float16)hi.y; f[6] = (_Float16)hi.z; f[7] = (_Float16)hi.w;
      Wf[i][ks] = f;
    }
  }
  float bias[2];
#pragma unroll
  for (int i = 0; i < 2; ++i) bias[i] = b_tree[(nbase + i) * 16 + l15];

  // ---- prologue: gather s0 of first pair (both halves) ----
  int tokS1lo = tokens[(2 * blockIdx.x + 1) * 128 + li];
  int tokS1hi = tokens[(2 * blockIdx.x + 1) * 128 + 64 + li];
  {
    const int tlo = tokens[(2 * blockIdx.x) * 128 + li];
    const int thi = tokens[(2 * blockIdx.x) * 128 + 64 + li];
    float4 st[8];
    load8(embedding, tlo, gq, st);
    cvt_write8(st, bufA, gr, glb, gq);
    load8(embedding, thi, gq, st);
    cvt_write8(st, bufA, 32 + gr, glb, gq);
  }
  __syncthreads();

#pragma unroll 1
  for (int p = blockIdx.x; p < NPAIR; p += (int)gridDim.x) {
    int pn = p + gridDim.x;
    if (pn >= NPAIR) pn = p;                   // last iter: harmless self-reload
    const bool first = (p == (int)blockIdx.x);
    const int pprev = p - (int)gridDim.x;
    const int tokN0lo = tokens[(2 * pn) * 128 + li];
    const int tokN0hi = tokens[(2 * pn) * 128 + 64 + li];

    // ---- phA: L5b(prev: C[0:4]->C[4:6], row-clamped) + L0 s0: A->B ----
    if (!first) {
      const int rc = l15 < 4 ? l15 : 3;
      floatx4 acc[2];
      mfma_k256(bufC + rc * STRIDE + quad * 8, Wf, bias, acc);
      const int mrow = quad * 4;
#pragma unroll
      for (int i = 0; i < 2; ++i) {
        const int col = (nbase + i) * 16 + l15;
#pragma unroll
        for (int r = 0; r < 4; ++r) {
          const int node = mrow + r;               // <4 valid: s=node>>1, ln=node&1
          if (node < 4) {
            float v = fast_tanh(acc[i][r]);
            bufC[(4 + (node >> 1)) * STRIDE + (node & 1) * 128 + col] = (_Float16)v;
          }
        }
      }
    }
    level_b<4, 64, -1>(bufA, bufB, Wf, bias, nbase, l15, quad);    // L0 s0
    __syncthreads();

    // ---- phB: L6b(prev: C[4:6])+classifier -> wavepart; L1 s0: B->A[0:16] ----
    if (!first) {
      const int rc = 4 + (l15 < 2 ? l15 : 1);
      floatx4 acc[2];
      mfma_k256(bufC + rc * STRIDE + quad * 8, Wf, bias, acc);
      float part[2][3] = {{0.f, 0.f, 0.f}, {0.f, 0.f, 0.f}};
      if (quad == 0) {
        float wcl[2][3];                           // reloaded per pair: stays transient
#pragma unroll
        for (int i = 0; i < 2; ++i)
#pragma unroll
          for (int o = 0; o < 3; ++o) wcl[i][o] = W_cls[o * 128 + (nbase + i) * 16 + l15];
#pragma unroll
        for (int i = 0; i < 2; ++i)
#pragma unroll
          for (int rr = 0; rr < 2; ++rr) {         // rr = sample (D rows 0,1)
            float v = fast_tanh(acc[i][rr]);
#pragma unroll
            for (int o = 0; o < 3; ++o) part[rr][o] = fmaf(v, wcl[i][o], part[rr][o]);
          }
      }
#pragma unroll
      for (int rr = 0; rr < 2; ++rr)
#pragma unroll
        for (int o = 0; o < 3; ++o) {
          float v = part[rr][o];                   // nonzero only in quad-0 lanes
          v += __shfl_down(v, 8);
          v += __shfl_down(v, 4);
          v += __shfl_down(v, 2);
          v += __shfl_down(v, 1);
          if (lane == 0) wavepart[wid][rr][o] = v;
        }
    }
    level_b<2, 32, -1>(bufB, bufA, Wf, bias, nbase, l15, quad);    // L1 s0 -> A[0:16]
    __syncthreads();

    // ---- phC: store(prev); L2 s0: A[0:16]->B[0:8]; gather s1-hi -> A[32:64] ----
    {
      float4 st[8];
      load8(embedding, tokS1hi, gq, st);           // issue first: latency under L2
      if (!first && tid < 6) {
        const int rr = tid / 3, o = tid - 3 * rr;
        float v = wavepart[0][rr][o] + wavepart[1][rr][o]
                + wavepart[2][rr][o] + wavepart[3][rr][o];
        out[(2 * pprev + rr) * 3 + o] = v + b_cls[o];
      }
      level_b<1, 16, -1>(bufA, bufB, Wf, bias, nbase, l15, quad);  // L2 s0
      cvt_write8(st, bufA, 32 + gr, glb, gq);
    }
    __syncthreads();

    // ---- phD: L3 s0: B[0:16]->B[16:20]; gather s1-lo -> A[0:32] ----
    {
      float4 st[8];
      load8(embedding, tokS1lo, gq, st);
      level_b<1, 8, 8>(bufB, bufB + 16 * STRIDE, Wf, bias, nbase, l15, quad);
      cvt_write8(st, bufA, gr, glb, gq);
    }
    __syncthreads();

    // ---- phE: L4 s0: B[16:32] (valid 16-19) -> C[0:2] ----
    level_b<1, 4, 4>(bufB + 16 * STRIDE, bufC, Wf, bias, nbase, l15, quad);
    __syncthreads();

    // ---- phF: L0 s1: A->B ----
    level_b<4, 64, -1>(bufA, bufB, Wf, bias, nbase, l15, quad);
    __syncthreads();

    // ---- phG: L1 s1: B->A[0:16]; gather next-s0-hi -> A[32:64] ----
    {
      float4 st[8];
      load8(embedding, tokN0hi, gq, st);
      level_b<2, 32, -1>(bufB, bufA, Wf, bias, nbase, l15, quad);
      cvt_write8(st, bufA, 32 + gr, glb, gq);
    }
    __syncthreads();

    // ---- phH: L2 s1: A[0:16]->B[0:8] ----
    level_b<1, 16, -1>(bufA, bufB, Wf, bias, nbase, l15, quad);
    __syncthreads();

    // ---- phI: L3 s1: B[0:16]->B[16:20]; gather next-s0-lo -> A[0:32] ----
    {
      float4 st[8];
      load8(embedding, tokN0lo, gq, st);
      level_b<1, 8, 8>(bufB, bufB + 16 * STRIDE, Wf, bias, nbase, l15, quad);
      cvt_write8(st, bufA, gr, glb, gq);
    }
    __syncthreads();

    // ---- phJ: L4 s1: B[16:32] (valid 16-19) -> C[2:4] ----
    level_b<1, 4, 4>(bufB + 16 * STRIDE, bufC + 2 * STRIDE, Wf, bias, nbase, l15, quad);
    __syncthreads();

    // next pair's s1 tokens (self-reload on final iter: harmless)
    tokS1lo = tokens[(2 * pn + 1) * 128 + li];
    tokS1hi = tokens[(2 * pn + 1) * 128 + 64 + li];
  }

  // ---- epilogue: L5b + L6b + classifier + store for the final pair ----
  {
    const int plast = (int)blockIdx.x
        + ((NPAIR - 1 - (int)blockIdx.x) / (int)gridDim.x) * (int)gridDim.x;
    {
      const int rc = l15 < 4 ? l15 : 3;
      floatx4 acc[2];
      mfma_k256(bufC + rc * STRIDE + quad * 8, Wf, bias, acc);
      const int mrow = quad * 4;
#pragma unroll
      for (int i = 0; i < 2; ++i) {
        const int col = (nbase + i) * 16 + l15;
#pragma unroll
        for (int r = 0; r < 4; ++r) {
          const int node = mrow + r;
          if (node < 4) {
            float v = fast_tanh(acc[i][r]);
            bufC[(4 + (node >> 1)) * STRIDE + (node & 1) * 128 + col] = (_Float16)v;
          }
        }
      }
    }
    __syncthreads();
    {
      const int rc = 4 + (l15 < 2 ? l15 : 1);
      floatx4 acc[2];
      mfma_k256(bufC + rc * STRIDE + quad * 8, Wf, bias, acc);
      float part[2][3] = {{0.f, 0.f, 0.f}, {0.f, 0.f, 0.f}};
      if (quad == 0) {
        float wcl[2][3];
#pragma unroll
        for (int i = 0; i < 2; ++i)
#pragma unroll
          for (int o = 0; o < 3; ++o) wcl[i][o] = W_cls[o * 128 + (nbase + i) * 16 + l15];
#pragma unroll
        for (int i = 0; i < 2; ++i)
#pragma unroll
          for (int rr = 0; rr < 2; ++rr) {
            float v = fast_tanh(acc[i][rr]);
#pragma unroll
            for (int o = 0; o < 3; ++o) part[rr][o] = fmaf(v, wcl[i][o], part[rr][o]);
          }
      }
#pragma unroll
      for (int rr = 0; rr < 2; ++rr)
#pragma unroll
        for (int o = 0; o < 3; ++o) {
          float v = part[rr][o];
          v += __shfl_down(v, 8);
          v += __shfl_down(v, 4);
          v += __shfl_down(v, 2);
          v += __shfl_down(v, 1);
          if (lane == 0) wavepart[wid][rr][o] = v;
        }
    }
    __syncthreads();
    if (tid < 6) {
      const int rr = tid / 3, o = tid - 3 * rr;
      float v = wavepart[0][rr][o] + wavepart[1][rr][o]
              + wavepart[2][rr][o] + wavepart[3][rr][o];
      out[(2 * plast + rr) * 3 + o] = v + b_cls[o];
    }
  }
}

extern "C" void kernel_launch(void* const* d_in, const int* in_sizes, int n_in,
                              void* d_out, int out_size, void* d_ws, size_t ws_size,
                              hipStream_t stream) {
  const int*   tokens    = (const int*)d_in[0];
  const float* embedding = (const float*)d_in[1];
  const float* W_tree    = (const float*)d_in[2];
  const float* b_tree    = (const float*)d_in[3];
  const float* W_cls     = (const float*)d_in[4];
  const float* b_cls     = (const float*)d_in[5];
  float* out = (float*)d_out;

  dim3 grid(768), block(256);   // 3 blocks/CU x 256 CUs; grid-stride over 2048 pairs
  tree_kernel<<<grid, block, 0, stream>>>(tokens, embedding, W_tree, b_tree, W_cls, b_cls, out);
}